// Round 2
// baseline (1114.913 us; speedup 1.0000x reference)
//
#include <hip/hip_runtime.h>
#include <hip/hip_bf16.h>
#include <cstdint>
#include <cstddef>

typedef unsigned short u16;
typedef short short8 __attribute__((ext_vector_type(8)));
typedef float floatx4 __attribute__((ext_vector_type(4)));

#define BM 128
#define BN 128
#define BK 32
#define D_DIM 2048

__device__ __forceinline__ void async_ld16(const u16* g, u16* l) {
  __builtin_amdgcn_global_load_lds(
      (const __attribute__((address_space(1))) void*)g,
      (__attribute__((address_space(3))) void*)l, 16, 0, 0);
}

__device__ __forceinline__ u16 f2bf(float f) {
  __hip_bfloat16 h = __float2bfloat16(f);
  return *reinterpret_cast<u16*>(&h);
}

__device__ __forceinline__ short8 pack8(float4 a, float4 b) {
  short8 p;
  p[0] = (short)f2bf(a.x); p[1] = (short)f2bf(a.y);
  p[2] = (short)f2bf(a.z); p[3] = (short)f2bf(a.w);
  p[4] = (short)f2bf(b.x); p[5] = (short)f2bf(b.y);
  p[6] = (short)f2bf(b.z); p[7] = (short)f2bf(b.w);
  return p;
}

// ---------------- fp32 -> bf16 weight conversion ----------------
__global__ __launch_bounds__(256) void cvt_f32_bf16(
    const float* __restrict__ src, u16* __restrict__ dst, int n8) {
  int i = blockIdx.x * blockDim.x + threadIdx.x;
  if (i < n8) {
    const float4* s = (const float4*)src + 2 * (size_t)i;
    float4 f0 = s[0], f1 = s[1];
    *((short8*)dst + i) = pack8(f0, f1);
  }
}

// ---------------- GEMM phase: A fp32 (VGPR-cvt staging), B bf16 (async) ----
// A: [M x K] fp32 row-major, Bw: [N x K] bf16 row-major (B^T layout).
__device__ __forceinline__ void phase_f32A(
    const float* __restrict__ A, const u16* __restrict__ Bw,
    int mBase, int nBase, u16* As, u16* Bs, floatx4 acc[4][4])
{
  const int tid  = threadIdx.x;
  const int lane = tid & 63;
  const int quad = lane >> 4;
  const int lrow = lane & 15;
  const int wv   = tid >> 6;
  const int wm   = wv & 1;
  const int wn   = wv >> 1;

  // B async staging: row r0 = tid>>2, col chunk (tid&3)*8  (bf16)
  const int r0 = tid >> 2;
  const int c0 = (tid & 3) * 8;
  const u16* gB = Bw + (size_t)(nBase + r0) * D_DIM + c0;
  u16* lB0 = Bs + tid * 8;
  u16* lB1 = Bs + (tid + 256) * 8;

  // A fp32 staging: row ar = tid>>1 (0..127), half ac = (tid&1)*16
  const int ar = tid >> 1;
  const int ac = (tid & 1) * 16;
  const float* gA = A + (size_t)(mBase + ar) * D_DIM + ac;
  u16* wA = As + ar * BK + ac;

  for (int kt = 0; kt < D_DIM / BK; ++kt) {
    const int k0 = kt * BK;
    __syncthreads();  // previous tile's LDS reads complete
    // issue async B loads first so they fly during A's cvt work
    async_ld16(gB + k0, lB0);
    async_ld16(gB + (size_t)64 * D_DIM + k0, lB1);
    // A: 16 fp32 -> 16 bf16 -> 2x ds_write_b128
    float4 f0 = *(const float4*)(gA + k0);
    float4 f1 = *(const float4*)(gA + k0 + 4);
    float4 f2 = *(const float4*)(gA + k0 + 8);
    float4 f3 = *(const float4*)(gA + k0 + 12);
    *(short8*)(wA)     = pack8(f0, f1);
    *(short8*)(wA + 8) = pack8(f2, f3);
    __syncthreads();  // drains vmcnt (async B) + lgkmcnt (ds_write)

    short8 a[4], b[4];
#pragma unroll
    for (int i = 0; i < 4; ++i) {
      const int row = wm * 64 + i * 16 + lrow;
      a[i] = *(const short8*)(As + row * BK + quad * 8);
      const int col = wn * 64 + i * 16 + lrow;
      b[i] = *(const short8*)(Bs + col * BK + quad * 8);
    }
#pragma unroll
    for (int i = 0; i < 4; ++i)
#pragma unroll
      for (int j = 0; j < 4; ++j)
        acc[i][j] = __builtin_amdgcn_mfma_f32_16x16x32_bf16(a[i], b[j], acc[i][j], 0, 0, 0);
  }
}

// ---------------- GEMM phase: A bf16 (async), B bf16 (async) ----------------
__device__ __forceinline__ void phase_bf16(
    const u16* __restrict__ A, const u16* __restrict__ Bw,
    int mBase, int nBase, u16* As, u16* Bs, floatx4 acc[4][4])
{
  const int tid  = threadIdx.x;
  const int lane = tid & 63;
  const int quad = lane >> 4;
  const int lrow = lane & 15;
  const int wv   = tid >> 6;
  const int wm   = wv & 1;
  const int wn   = wv >> 1;

  const int r0 = tid >> 2;
  const int c0 = (tid & 3) * 8;
  const u16* gA = A + (size_t)(mBase + r0) * D_DIM + c0;
  const u16* gB = Bw + (size_t)(nBase + r0) * D_DIM + c0;
  u16* lA0 = As + tid * 8;
  u16* lA1 = As + (tid + 256) * 8;
  u16* lB0 = Bs + tid * 8;
  u16* lB1 = Bs + (tid + 256) * 8;

  for (int kt = 0; kt < D_DIM / BK; ++kt) {
    const int k0 = kt * BK;
    __syncthreads();
    async_ld16(gA + k0, lA0);
    async_ld16(gA + (size_t)64 * D_DIM + k0, lA1);
    async_ld16(gB + k0, lB0);
    async_ld16(gB + (size_t)64 * D_DIM + k0, lB1);
    __syncthreads();

    short8 a[4], b[4];
#pragma unroll
    for (int i = 0; i < 4; ++i) {
      const int row = wm * 64 + i * 16 + lrow;
      a[i] = *(const short8*)(As + row * BK + quad * 8);
      const int col = wn * 64 + i * 16 + lrow;
      b[i] = *(const short8*)(Bs + col * BK + quad * 8);
    }
#pragma unroll
    for (int i = 0; i < 4; ++i)
#pragma unroll
      for (int j = 0; j < 4; ++j)
        acc[i][j] = __builtin_amdgcn_mfma_f32_16x16x32_bf16(a[i], b[j], acc[i][j], 0, 0, 0);
  }
}

// pp = tanh(li*W1^T + x*W2^T + b1 + b2)  (fp32 in, bf16 out)
__global__ __launch_bounds__(256) void gemm_pp_kernel(
    const float* __restrict__ li, const float* __restrict__ x,
    const u16* __restrict__ w1b, const u16* __restrict__ w2b,
    const float* __restrict__ b1, const float* __restrict__ b2,
    u16* __restrict__ pp)
{
  __shared__ __align__(16) u16 As[BM * BK];
  __shared__ __align__(16) u16 Bs[BN * BK];

  floatx4 acc[4][4];
#pragma unroll
  for (int i = 0; i < 4; ++i)
#pragma unroll
    for (int j = 0; j < 4; ++j)
      acc[i][j] = (floatx4){0.f, 0.f, 0.f, 0.f};

  const int nBase = blockIdx.x * BN;  // n-tile fastest: A-slab reuse in L2
  const int mBase = blockIdx.y * BM;

  phase_f32A(li, w1b, mBase, nBase, As, Bs, acc);
  phase_f32A(x,  w2b, mBase, nBase, As, Bs, acc);

  const int tid  = threadIdx.x;
  const int lane = tid & 63;
  const int quad = lane >> 4;
  const int lrow = lane & 15;
  const int wv   = tid >> 6;
  const int wm   = wv & 1;
  const int wn   = wv >> 1;

#pragma unroll
  for (int j = 0; j < 4; ++j) {
    const int col = nBase + wn * 64 + j * 16 + lrow;
    const float bs = b1[col] + b2[col];
#pragma unroll
    for (int i = 0; i < 4; ++i) {
      const int rowb = mBase + wm * 64 + i * 16 + quad * 4;
#pragma unroll
      for (int r = 0; r < 4; ++r) {
        const float v = tanhf(acc[i][j][r] + bs);
        pp[(size_t)(rowb + r) * D_DIM + col] = f2bf(v);
      }
    }
  }
}

// out = sigmoid(pp*V^T + bV) * pe  (pp bf16, rest fp32)
__global__ __launch_bounds__(256) void gemm_out_kernel(
    const u16* __restrict__ pp, const u16* __restrict__ vb,
    const float* __restrict__ bV, const float* __restrict__ pe,
    float* __restrict__ out)
{
  __shared__ __align__(16) u16 As[BM * BK];
  __shared__ __align__(16) u16 Bs[BN * BK];

  floatx4 acc[4][4];
#pragma unroll
  for (int i = 0; i < 4; ++i)
#pragma unroll
    for (int j = 0; j < 4; ++j)
      acc[i][j] = (floatx4){0.f, 0.f, 0.f, 0.f};

  const int nBase = blockIdx.x * BN;
  const int mBase = blockIdx.y * BM;

  phase_bf16(pp, vb, mBase, nBase, As, Bs, acc);

  const int tid  = threadIdx.x;
  const int lane = tid & 63;
  const int quad = lane >> 4;
  const int lrow = lane & 15;
  const int wv   = tid >> 6;
  const int wm   = wv & 1;
  const int wn   = wv >> 1;

#pragma unroll
  for (int j = 0; j < 4; ++j) {
    const int col = nBase + wn * 64 + j * 16 + lrow;
    const float bs = bV[col];
#pragma unroll
    for (int i = 0; i < 4; ++i) {
      const int rowb = mBase + wm * 64 + i * 16 + quad * 4;
#pragma unroll
      for (int r = 0; r < 4; ++r) {
        const size_t idx = (size_t)(rowb + r) * D_DIM + col;
        const float t = acc[i][j][r] + bs;
        const float g = 1.f / (1.f + expf(-t));
        out[idx] = g * pe[idx];
      }
    }
  }
}

extern "C" void kernel_launch(void* const* d_in, const int* in_sizes, int n_in,
                              void* d_out, int out_size, void* d_ws, size_t ws_size,
                              hipStream_t stream) {
  // setup_inputs order: x, layer_input, position_embedding, mask, langs,
  //                     W1, b1, W2, b2, V, bV  -- all floats are fp32
  const float* x  = (const float*)d_in[0];
  const float* li = (const float*)d_in[1];
  const float* pe = (const float*)d_in[2];
  const float* W1 = (const float*)d_in[5];
  const float* b1 = (const float*)d_in[6];
  const float* W2 = (const float*)d_in[7];
  const float* b2 = (const float*)d_in[8];
  const float* V  = (const float*)d_in[9];
  const float* bV = (const float*)d_in[10];
  float* out = (float*)d_out;

  // ws layout (bf16): w1b | w2b | vb (4M elems each) | pp (16384x2048)
  u16* w1b = (u16*)d_ws;
  u16* w2b = w1b + (size_t)D_DIM * D_DIM;
  u16* vb  = w2b + (size_t)D_DIM * D_DIM;
  u16* pp  = vb  + (size_t)D_DIM * D_DIM;   // total 88 MiB

  const int M = 2048 * 8;  // S*B
  const int nW8 = (D_DIM * D_DIM) / 8;  // 524288

  cvt_f32_bf16<<<nW8 / 256, 256, 0, stream>>>(W1, w1b, nW8);
  cvt_f32_bf16<<<nW8 / 256, 256, 0, stream>>>(W2, w2b, nW8);
  cvt_f32_bf16<<<nW8 / 256, 256, 0, stream>>>(V,  vb,  nW8);

  dim3 grid(D_DIM / BN, M / BM);  // (16, 128): n-tile fastest
  dim3 block(256);
  gemm_pp_kernel<<<grid, block, 0, stream>>>(li, x, w1b, w2b, b1, b2, pp);
  gemm_out_kernel<<<grid, block, 0, stream>>>(pp, vb, bV, pe, out);
}

// Round 3
// 1053.143 us; speedup vs baseline: 1.0587x; 1.0587x over previous
//
#include <hip/hip_runtime.h>
#include <hip/hip_bf16.h>
#include <cstdint>
#include <cstddef>

typedef unsigned short u16;
typedef short short8 __attribute__((ext_vector_type(8)));
typedef float floatx4 __attribute__((ext_vector_type(4)));

#define BM 128
#define BN 128
#define BK 32
#define D_DIM 2048

__device__ __forceinline__ void async_ld16(const u16* g, u16* l) {
  __builtin_amdgcn_global_load_lds(
      (const __attribute__((address_space(1))) void*)g,
      (__attribute__((address_space(3))) void*)l, 16, 0, 0);
}

__device__ __forceinline__ u16 f2bf(float f) {
  __hip_bfloat16 h = __float2bfloat16(f);
  return *reinterpret_cast<u16*>(&h);
}

__device__ __forceinline__ short8 pack8(float4 a, float4 b) {
  short8 p;
  p[0] = (short)f2bf(a.x); p[1] = (short)f2bf(a.y);
  p[2] = (short)f2bf(a.z); p[3] = (short)f2bf(a.w);
  p[4] = (short)f2bf(b.x); p[5] = (short)f2bf(b.y);
  p[6] = (short)f2bf(b.z); p[7] = (short)f2bf(b.w);
  return p;
}

// ---------------- fp32 -> bf16 conversion ----------------
__global__ __launch_bounds__(256) void cvt_f32_bf16(
    const float* __restrict__ src, u16* __restrict__ dst, int n8) {
  int i = blockIdx.x * blockDim.x + threadIdx.x;
  if (i < n8) {
    const float4* s = (const float4*)src + 2 * (size_t)i;
    float4 f0 = s[0], f1 = s[1];
    *((short8*)dst + i) = pack8(f0, f1);
  }
}

// ============ pure-async bf16 phase with XOR-swizzled LDS chunks ============
// LDS slot (row, c) holds global chunk (row, c ^ ((row>>1)&3)).
// Staging lane (r0 = tid>>2, c = tid&3) loads global chunk q0 = c ^ ((r0>>1)&3)
// into its fixed LDS slot; reader of (row, quad) uses slot quad ^ ((row>>1)&3).
// Bank math: dword-group (16*(row&1) + 4*slot)%32 now covers all 8 groups
// exactly twice per quad -> 2-way aliasing (free, m136).
__device__ __forceinline__ void phase_bf16(
    const u16* __restrict__ A, const u16* __restrict__ Bw,
    int mBase, int nBase, u16* As, u16* Bs, floatx4 acc[4][4])
{
  const int tid  = threadIdx.x;
  const int lane = tid & 63;
  const int quad = lane >> 4;
  const int lrow = lane & 15;
  const int wv   = tid >> 6;
  const int wm   = wv & 1;
  const int wn   = wv >> 1;

  const int r0 = tid >> 2;
  const int q0 = (((tid & 3) ^ ((tid >> 3) & 3))) * 8;  // swizzled global chunk
  const u16* gA = A + (size_t)(mBase + r0) * D_DIM + q0;
  const u16* gB = Bw + (size_t)(nBase + r0) * D_DIM + q0;
  u16* lA0 = As + tid * 8;
  u16* lA1 = As + (tid + 256) * 8;
  u16* lB0 = Bs + tid * 8;
  u16* lB1 = Bs + (tid + 256) * 8;

  const int slot8 = (quad ^ ((lrow >> 1) & 3)) * 8;  // read-side swizzle

  for (int kt = 0; kt < D_DIM / BK; ++kt) {
    const int k0 = kt * BK;
    __syncthreads();
    async_ld16(gA + k0, lA0);
    async_ld16(gA + (size_t)64 * D_DIM + k0, lA1);
    async_ld16(gB + k0, lB0);
    async_ld16(gB + (size_t)64 * D_DIM + k0, lB1);
    __syncthreads();

    short8 a[4], b[4];
#pragma unroll
    for (int i = 0; i < 4; ++i) {
      const int row = wm * 64 + i * 16 + lrow;
      a[i] = *(const short8*)(As + row * BK + slot8);
      const int col = wn * 64 + i * 16 + lrow;
      b[i] = *(const short8*)(Bs + col * BK + slot8);
    }
#pragma unroll
    for (int i = 0; i < 4; ++i)
#pragma unroll
      for (int j = 0; j < 4; ++j)
        acc[i][j] = __builtin_amdgcn_mfma_f32_16x16x32_bf16(a[i], b[j], acc[i][j], 0, 0, 0);
  }
}

// ---------------- fallback phase: A fp32 VGPR-cvt staging (round-2) --------
__device__ __forceinline__ void phase_f32A(
    const float* __restrict__ A, const u16* __restrict__ Bw,
    int mBase, int nBase, u16* As, u16* Bs, floatx4 acc[4][4])
{
  const int tid  = threadIdx.x;
  const int lane = tid & 63;
  const int quad = lane >> 4;
  const int lrow = lane & 15;
  const int wv   = tid >> 6;
  const int wm   = wv & 1;
  const int wn   = wv >> 1;

  const int r0 = tid >> 2;
  const int c0 = (tid & 3) * 8;
  const u16* gB = Bw + (size_t)(nBase + r0) * D_DIM + c0;
  u16* lB0 = Bs + tid * 8;
  u16* lB1 = Bs + (tid + 256) * 8;

  const int ar = tid >> 1;
  const int ac = (tid & 1) * 16;
  const float* gA = A + (size_t)(mBase + ar) * D_DIM + ac;
  u16* wA = As + ar * BK + ac;

  for (int kt = 0; kt < D_DIM / BK; ++kt) {
    const int k0 = kt * BK;
    __syncthreads();
    async_ld16(gB + k0, lB0);
    async_ld16(gB + (size_t)64 * D_DIM + k0, lB1);
    float4 f0 = *(const float4*)(gA + k0);
    float4 f1 = *(const float4*)(gA + k0 + 4);
    float4 f2 = *(const float4*)(gA + k0 + 8);
    float4 f3 = *(const float4*)(gA + k0 + 12);
    *(short8*)(wA)     = pack8(f0, f1);
    *(short8*)(wA + 8) = pack8(f2, f3);
    __syncthreads();

    short8 a[4], b[4];
#pragma unroll
    for (int i = 0; i < 4; ++i) {
      const int row = wm * 64 + i * 16 + lrow;
      a[i] = *(const short8*)(As + row * BK + quad * 8);
      const int col = wn * 64 + i * 16 + lrow;
      b[i] = *(const short8*)(Bs + col * BK + quad * 8);
    }
#pragma unroll
    for (int i = 0; i < 4; ++i)
#pragma unroll
      for (int j = 0; j < 4; ++j)
        acc[i][j] = __builtin_amdgcn_mfma_f32_16x16x32_bf16(a[i], b[j], acc[i][j], 0, 0, 0);
  }
}

// ---------------- epilogues ----------------
__device__ __forceinline__ void epilogue_pp(
    floatx4 acc[4][4], const float* b1, const float* b2,
    int mBase, int nBase, u16* pp)
{
  const int tid  = threadIdx.x;
  const int lane = tid & 63;
  const int quad = lane >> 4;
  const int lrow = lane & 15;
  const int wv   = tid >> 6;
  const int wm   = wv & 1;
  const int wn   = wv >> 1;

#pragma unroll
  for (int j = 0; j < 4; ++j) {
    const int col = nBase + wn * 64 + j * 16 + lrow;
    const float bs = b1[col] + b2[col];
#pragma unroll
    for (int i = 0; i < 4; ++i) {
      const int rowb = mBase + wm * 64 + i * 16 + quad * 4;
#pragma unroll
      for (int r = 0; r < 4; ++r) {
        const float v = tanhf(acc[i][j][r] + bs);
        pp[(size_t)(rowb + r) * D_DIM + col] = f2bf(v);
      }
    }
  }
}

// pp = tanh(li*W1^T + x*W2^T + b1 + b2), all-bf16 path
__global__ __launch_bounds__(256) void gemm_pp_bf16(
    const u16* __restrict__ lib, const u16* __restrict__ xb,
    const u16* __restrict__ w1b, const u16* __restrict__ w2b,
    const float* __restrict__ b1, const float* __restrict__ b2,
    u16* __restrict__ pp)
{
  __shared__ __align__(16) u16 As[BM * BK];
  __shared__ __align__(16) u16 Bs[BN * BK];

  floatx4 acc[4][4];
#pragma unroll
  for (int i = 0; i < 4; ++i)
#pragma unroll
    for (int j = 0; j < 4; ++j)
      acc[i][j] = (floatx4){0.f, 0.f, 0.f, 0.f};

  const int nBase = blockIdx.x * BN;
  const int mBase = blockIdx.y * BM;

  phase_bf16(lib, w1b, mBase, nBase, As, Bs, acc);
  phase_bf16(xb,  w2b, mBase, nBase, As, Bs, acc);
  epilogue_pp(acc, b1, b2, mBase, nBase, pp);
}

// pp = tanh(...) fallback: fp32 A in-loop cvt
__global__ __launch_bounds__(256) void gemm_pp_f32(
    const float* __restrict__ li, const float* __restrict__ x,
    const u16* __restrict__ w1b, const u16* __restrict__ w2b,
    const float* __restrict__ b1, const float* __restrict__ b2,
    u16* __restrict__ pp)
{
  __shared__ __align__(16) u16 As[BM * BK];
  __shared__ __align__(16) u16 Bs[BN * BK];

  floatx4 acc[4][4];
#pragma unroll
  for (int i = 0; i < 4; ++i)
#pragma unroll
    for (int j = 0; j < 4; ++j)
      acc[i][j] = (floatx4){0.f, 0.f, 0.f, 0.f};

  const int nBase = blockIdx.x * BN;
  const int mBase = blockIdx.y * BM;

  phase_f32A(li, w1b, mBase, nBase, As, Bs, acc);
  phase_f32A(x,  w2b, mBase, nBase, As, Bs, acc);
  epilogue_pp(acc, b1, b2, mBase, nBase, pp);
}

// out = sigmoid(pp*V^T + bV) * pe
__global__ __launch_bounds__(256) void gemm_out_kernel(
    const u16* __restrict__ pp, const u16* __restrict__ vb,
    const float* __restrict__ bV, const float* __restrict__ pe,
    float* __restrict__ out)
{
  __shared__ __align__(16) u16 As[BM * BK];
  __shared__ __align__(16) u16 Bs[BN * BK];

  floatx4 acc[4][4];
#pragma unroll
  for (int i = 0; i < 4; ++i)
#pragma unroll
    for (int j = 0; j < 4; ++j)
      acc[i][j] = (floatx4){0.f, 0.f, 0.f, 0.f};

  const int nBase = blockIdx.x * BN;
  const int mBase = blockIdx.y * BM;

  phase_bf16(pp, vb, mBase, nBase, As, Bs, acc);

  const int tid  = threadIdx.x;
  const int lane = tid & 63;
  const int quad = lane >> 4;
  const int lrow = lane & 15;
  const int wv   = tid >> 6;
  const int wm   = wv & 1;
  const int wn   = wv >> 1;

#pragma unroll
  for (int j = 0; j < 4; ++j) {
    const int col = nBase + wn * 64 + j * 16 + lrow;
    const float bs = bV[col];
#pragma unroll
    for (int i = 0; i < 4; ++i) {
      const int rowb = mBase + wm * 64 + i * 16 + quad * 4;
#pragma unroll
      for (int r = 0; r < 4; ++r) {
        const size_t idx = (size_t)(rowb + r) * D_DIM + col;
        const float t = acc[i][j][r] + bs;
        const float g = 1.f / (1.f + expf(-t));
        out[idx] = g * pe[idx];
      }
    }
  }
}

extern "C" void kernel_launch(void* const* d_in, const int* in_sizes, int n_in,
                              void* d_out, int out_size, void* d_ws, size_t ws_size,
                              hipStream_t stream) {
  const float* x  = (const float*)d_in[0];
  const float* li = (const float*)d_in[1];
  const float* pe = (const float*)d_in[2];
  const float* W1 = (const float*)d_in[5];
  const float* b1 = (const float*)d_in[6];
  const float* W2 = (const float*)d_in[7];
  const float* b2 = (const float*)d_in[8];
  const float* V  = (const float*)d_in[9];
  const float* bV = (const float*)d_in[10];
  float* out = (float*)d_out;

  const int M = 2048 * 8;                      // S*B = 16384
  const size_t nW  = (size_t)D_DIM * D_DIM;    // 4.19M
  const size_t nA  = (size_t)M * D_DIM;        // 33.5M

  // ws layout (u16 elems): w1b | w2b | vb | pp | lib | xb
  u16* w1b = (u16*)d_ws;
  u16* w2b = w1b + nW;
  u16* vb  = w2b + nW;
  u16* pp  = vb  + nW;
  u16* lib = pp  + nA;
  u16* xb  = lib + nA;
  const size_t need_full = (3 * nW + 3 * nA) * sizeof(u16);  // ~226 MB

  const int nW8 = (int)(nW / 8);
  const int nA8 = (int)(nA / 8);

  cvt_f32_bf16<<<nW8 / 256, 256, 0, stream>>>(W1, w1b, nW8);
  cvt_f32_bf16<<<nW8 / 256, 256, 0, stream>>>(W2, w2b, nW8);
  cvt_f32_bf16<<<nW8 / 256, 256, 0, stream>>>(V,  vb,  nW8);

  dim3 grid(D_DIM / BN, M / BM);  // (16, 128), n-tile fastest
  dim3 block(256);

  if (ws_size >= need_full) {
    cvt_f32_bf16<<<nA8 / 256, 256, 0, stream>>>(li, lib, nA8);
    cvt_f32_bf16<<<nA8 / 256, 256, 0, stream>>>(x,  xb,  nA8);
    gemm_pp_bf16<<<grid, block, 0, stream>>>(lib, xb, w1b, w2b, b1, b2, pp);
  } else {
    gemm_pp_f32<<<grid, block, 0, stream>>>(li, x, w1b, w2b, b1, b2, pp);
  }
  gemm_out_kernel<<<grid, block, 0, stream>>>(pp, vb, bV, pe, out);
}